// Round 11
// baseline (215.007 us; speedup 1.0000x reference)
//
#include <hip/hip_runtime.h>
#include <hip/hip_fp16.h>
#include <stdint.h>

// L=512, B=4, E=512, H=8, D=64
// R11: stream kernels use global_load_lds DMA staging (wave-private, dbuf,
// counted vmcnt, no barriers in stream). Rest identical to R10/R9 best.

typedef short short8 __attribute__((ext_vector_type(8)));
typedef float f32x4 __attribute__((ext_vector_type(4)));
typedef unsigned short u16x4 __attribute__((ext_vector_type(4)));

typedef __attribute__((address_space(3))) uint32_t lds_u32;
typedef __attribute__((address_space(1))) uint32_t glob_u32;

static __device__ __forceinline__ uint16_t f2bf(float f) {
  uint32_t u = __float_as_uint(f);
  uint32_t r = (u + 0x7FFFu + ((u >> 16) & 1u)) >> 16;
  return (uint16_t)r;
}
static __device__ __forceinline__ float bf2f(uint16_t h) {
  return __uint_as_float(((uint32_t)h) << 16);
}
static __device__ __forceinline__ short8 ld8(const uint16_t* p) {
  return *(const short8*)p;
}
static __device__ __forceinline__ void gload_lds16(const float* g, float* l) {
  __builtin_amdgcn_global_load_lds((const glob_u32*)g, (lds_u32*)l, 16, 0, 0);
}
#define MFMA(a, b, c) __builtin_amdgcn_mfma_f32_16x16x32_bf16((a), (b), (c), 0, 0, 0)

// ---------------- K0: merged fp32 -> bf16 conversions ----------------
__global__ __launch_bounds__(256) void k_conv_all(
    const float* __restrict__ in_w, const float* __restrict__ query,
    const float* __restrict__ out_w, uint16_t* __restrict__ w_hi,
    uint16_t* __restrict__ w_lo, uint16_t* __restrict__ a_hi,
    uint16_t* __restrict__ a_lo, uint16_t* __restrict__ wo_bf) {
  int e = (blockIdx.x * 256 + threadIdx.x) * 4;
  if (e < 786432) {
    f32x4 v = *(const f32x4*)(in_w + e);
    u16x4 hi, lo;
#pragma unroll
    for (int k = 0; k < 4; ++k) {
      hi[k] = f2bf(v[k]);
      lo[k] = f2bf(v[k] - bf2f(hi[k]));
    }
    *(u16x4*)(w_hi + e) = hi;
    *(u16x4*)(w_lo + e) = lo;
  } else if (e < 786432 + 1048576) {
    int o = e - 786432;
    f32x4 v = *(const f32x4*)(query + o);
    u16x4 hi, lo;
#pragma unroll
    for (int k = 0; k < 4; ++k) {
      hi[k] = f2bf(v[k]);
      lo[k] = f2bf(v[k] - bf2f(hi[k]));
    }
    *(u16x4*)(a_hi + o) = hi;
    *(u16x4*)(a_lo + o) = lo;
  } else {
    int o = e - 1835008;
    f32x4 v = *(const f32x4*)(out_w + o);
    u16x4 hi;
#pragma unroll
    for (int k = 0; k < 4; ++k) hi[k] = f2bf(v[k]);
    *(u16x4*)(wo_bf + o) = hi;
  }
}

// ---------------- K1: in_proj split-bf16 MFMA GEMM ----------------
__global__ __launch_bounds__(256) void k_inproj(
    const uint16_t* __restrict__ a_hi, const uint16_t* __restrict__ a_lo,
    const uint16_t* __restrict__ w_hi, const uint16_t* __restrict__ w_lo,
    const float* __restrict__ bias, float* __restrict__ q_s,
    uint16_t* __restrict__ q_bf, uint16_t* __restrict__ k_bf,
    uint16_t* __restrict__ v_bf) {
  const int wave = threadIdx.x >> 6, lane = threadIdx.x & 63;
  const int wr = wave >> 1, wc = wave & 1;
  const int rif = lane & 15, kg = lane >> 4;
  const int rbase = blockIdx.x * 64 + wr * 32;
  const int cbase = blockIdx.y * 64 + wc * 32;
  f32x4 acc[2][2] = {};
  for (int ks = 0; ks < 512; ks += 32) {
    int kofs = ks + kg * 8;
    short8 aH[2], aL[2], bH[2], bL[2];
#pragma unroll
    for (int m = 0; m < 2; ++m) {
      size_t idx = (size_t)(rbase + m * 16 + rif) * 512 + kofs;
      aH[m] = ld8(a_hi + idx);
      aL[m] = ld8(a_lo + idx);
    }
#pragma unroll
    for (int n = 0; n < 2; ++n) {
      size_t idx = (size_t)(cbase + n * 16 + rif) * 512 + kofs;
      bH[n] = ld8(w_hi + idx);
      bL[n] = ld8(w_lo + idx);
    }
#pragma unroll
    for (int m = 0; m < 2; ++m)
#pragma unroll
      for (int n = 0; n < 2; ++n) {
        acc[m][n] = MFMA(aH[m], bH[n], acc[m][n]);
        acc[m][n] = MFMA(aH[m], bL[n], acc[m][n]);
        acc[m][n] = MFMA(aL[m], bH[n], acc[m][n]);
      }
  }
#pragma unroll
  for (int m = 0; m < 2; ++m)
#pragma unroll
    for (int n = 0; n < 2; ++n)
#pragma unroll
      for (int r = 0; r < 4; ++r) {
        int row = rbase + m * 16 + kg * 4 + r;
        int col = cbase + n * 16 + rif;
        float val = acc[m][n][r] + bias[col];
        int l = row >> 2, b = row & 3;
        int sel = col >> 9, h = (col >> 6) & 7, d = col & 63;
        size_t oidx = ((size_t)(b * 8 + h) * 512 + l) * 64 + d;
        if (sel == 0) {
          val *= 0.125f;  // 1/sqrt(64)
          q_s[oidx] = val;
          q_bf[oidx] = f2bf(val);
        } else if (sel == 1) {
          k_bf[oidx] = f2bf(val);
        } else {
          v_bf[oidx] = f2bf(val);
        }
      }
}

// ---------------- K2: content scores per (b,h), fp16 output ----------------
__global__ __launch_bounds__(256) void k_scores(const uint16_t* __restrict__ q_bf,
                                                const uint16_t* __restrict__ k_bf,
                                                __half* __restrict__ scores) {
  const int bh = blockIdx.x;
  const uint16_t* qb = q_bf + (size_t)bh * 512 * 64;
  const uint16_t* kb = k_bf + (size_t)bh * 512 * 64;
  const int wave = threadIdx.x >> 6, lane = threadIdx.x & 63;
  const int wr = wave >> 1, wc = wave & 1;
  const int rif = lane & 15, kg = lane >> 4;
  const int ibase = blockIdx.y * 64 + wr * 32;
  const int jbase = blockIdx.z * 64 + wc * 32;
  f32x4 acc[2][2] = {};
#pragma unroll
  for (int ks = 0; ks < 64; ks += 32) {
    int kofs = ks + kg * 8;
    short8 A[2], Bb[2];
#pragma unroll
    for (int m = 0; m < 2; ++m) A[m] = ld8(qb + (size_t)(ibase + m * 16 + rif) * 64 + kofs);
#pragma unroll
    for (int n = 0; n < 2; ++n) Bb[n] = ld8(kb + (size_t)(jbase + n * 16 + rif) * 64 + kofs);
#pragma unroll
    for (int m = 0; m < 2; ++m)
#pragma unroll
      for (int n = 0; n < 2; ++n) acc[m][n] = MFMA(A[m], Bb[n], acc[m][n]);
  }
  __half* sc = scores + (size_t)bh * 512 * 512;
#pragma unroll
  for (int m = 0; m < 2; ++m)
#pragma unroll
    for (int n = 0; n < 2; ++n)
#pragma unroll
      for (int r = 0; r < 4; ++r)
        sc[(size_t)(ibase + m * 16 + kg * 4 + r) * 512 + (jbase + n * 16 + rif)] =
            __float2half(acc[m][n][r]);
}

// ---------------- K3: rksm5 — rk einsum via global_load_lds DMA + softmax ----------------
// wave w owns j-window [w*128, w*128+128); lane: jq=lane&31, dh=lane>>5.
// Chunk c stages d-rows {2c+dh} of the wave's window (1KB/wave call) into
// wave-private LDS; consume needs only the wave's own data -> no barriers.
// sx region (16KB) doubles as the stage area (first 8KB) during the stream.
__global__ __launch_bounds__(256) void k_rksm5(
    const float* __restrict__ relation_k, const float* __restrict__ q_s,
    const __half* __restrict__ scores, uint16_t* __restrict__ wprob) {
  __shared__ float qh[512];    // [d][h] 2 KB
  __shared__ float sxs[4096];  // 16 KB: stream = stage[2][4][256]; then sx[h][j]
  const int b = blockIdx.x >> 9, i = blockIdx.x & 511;
  const int t = threadIdx.x;
  const int wave = t >> 6, lane = t & 63;
  for (int e = t; e < 512; e += 256) {
    int h = e >> 6, d = e & 63;
    qh[d * 8 + h] = q_s[(((size_t)b * 8 + h) * 512 + i) * 64 + d];
  }
  __syncthreads();
  const int jq = lane & 31, dh = lane >> 5;
  const int j0 = wave * 128 + jq * 4;
  const float* rkb = relation_k + ((size_t)b * 512 + i) * 32768;
  f32x4 acc[8];
#pragma unroll
  for (int h = 0; h < 8; ++h) acc[h] = f32x4{0.f, 0.f, 0.f, 0.f};
  {
    // stage chunk c: per-lane global src rk[2c+dh][w*128 + jq*4 ..], LDS linear
    auto STAGE = [&](int c, int buf) {
      const float* g = rkb + (size_t)(2 * c + dh) * 512 + wave * 128 + jq * 4;
      gload_lds16(g, &sxs[buf * 1024 + wave * 256]);
    };
    STAGE(0, 0);
    int buf = 0;
#pragma unroll 4
    for (int c = 0; c < 32; ++c) {
      if (c < 31) {
        STAGE(c + 1, buf ^ 1);
        asm volatile("s_waitcnt vmcnt(1)" ::: "memory");
      } else {
        asm volatile("s_waitcnt vmcnt(0)" ::: "memory");
      }
      __builtin_amdgcn_sched_barrier(0);
      int d = 2 * c + dh;
      f32x4 kv = *(const f32x4*)&sxs[buf * 1024 + wave * 256 + dh * 128 + jq * 4];
      f32x4 qA = *(const f32x4*)&qh[d * 8];
      f32x4 qB = *(const f32x4*)&qh[d * 8 + 4];
#pragma unroll
      for (int h = 0; h < 4; ++h) {
        acc[h] += qA[h] * kv;
        acc[4 + h] += qB[h] * kv;
      }
      buf ^= 1;
    }
  }
  // combine d-parities in-register (lane l <-> l^32, same jq)
#pragma unroll
  for (int h = 0; h < 8; ++h)
#pragma unroll
    for (int c = 0; c < 4; ++c) acc[h][c] += __shfl_xor(acc[h][c], 32);
  __syncthreads();  // all waves done streaming; sxs becomes sx[h][j]
  if (dh == 0) {
#pragma unroll
    for (int h = 0; h < 8; ++h) *(f32x4*)&sxs[h * 512 + j0] = acc[h];
  }
  __syncthreads();
  // softmax (wave -> heads 2w, 2w+1); write wprob bf16
#pragma unroll
  for (int hh = 0; hh < 2; ++hh) {
    int h = wave * 2 + hh;
    const __half* srow = scores + (((size_t)b * 8 + h) * 512 + i) * 512;
    float s[8], m = -1e30f;
#pragma unroll
    for (int jj = 0; jj < 8; ++jj) {
      int j = jj * 64 + lane;
      s[jj] = __half2float(srow[j]) + sxs[h * 512 + j];
      m = fmaxf(m, s[jj]);
    }
    for (int o = 32; o > 0; o >>= 1) m = fmaxf(m, __shfl_xor(m, o));
    float ex[8], sum = 0.f;
#pragma unroll
    for (int jj = 0; jj < 8; ++jj) {
      ex[jj] = __expf(s[jj] - m);
      sum += ex[jj];
    }
    for (int o = 32; o > 0; o >>= 1) sum += __shfl_xor(sum, o);
    float r = 1.f / sum;
    uint16_t* wrow = wprob + (((size_t)b * 8 + h) * 512 + i) * 512;
#pragma unroll
    for (int jj = 0; jj < 8; ++jj) wrow[jj * 64 + lane] = f2bf(ex[jj] * r);
  }
}

// ---------------- K4: PV MFMA per (b,h), strided v loads ----------------
__global__ __launch_bounds__(256) void k_pv(const uint16_t* __restrict__ w_bf,
                                            const uint16_t* __restrict__ v_bf,
                                            uint16_t* __restrict__ pv_bf) {
  const int bh = blockIdx.x;
  const int b = bh >> 3, h = bh & 7;
  const uint16_t* wb = w_bf + (size_t)bh * 512 * 512;
  const uint16_t* vb = v_bf + (size_t)bh * 512 * 64;  // [j][d]
  const int wave = threadIdx.x >> 6, lane = threadIdx.x & 63;
  const int wr = wave >> 1, wc = wave & 1;
  const int rif = lane & 15, kg = lane >> 4;
  const int ibase = blockIdx.y * 64 + wr * 32;
  const int dbase = wc * 32;
  f32x4 acc[2][2] = {};
  for (int ks = 0; ks < 512; ks += 32) {
    int kofs = ks + kg * 8;
    short8 A[2], Bb[2];
#pragma unroll
    for (int m = 0; m < 2; ++m) A[m] = ld8(wb + (size_t)(ibase + m * 16 + rif) * 512 + kofs);
#pragma unroll
    for (int n = 0; n < 2; ++n) {
      uint16_t tb[8];
#pragma unroll
      for (int e = 0; e < 8; ++e) tb[e] = vb[(size_t)(kofs + e) * 64 + dbase + n * 16 + rif];
      Bb[n] = *(const short8*)tb;
    }
#pragma unroll
    for (int m = 0; m < 2; ++m)
#pragma unroll
      for (int n = 0; n < 2; ++n) acc[m][n] = MFMA(A[m], Bb[n], acc[m][n]);
  }
#pragma unroll
  for (int m = 0; m < 2; ++m)
#pragma unroll
    for (int n = 0; n < 2; ++n)
#pragma unroll
      for (int r = 0; r < 4; ++r) {
        int i = ibase + m * 16 + kg * 4 + r;
        int d = dbase + n * 16 + rif;
        pv_bf[((size_t)i * 4 + b) * 512 + h * 64 + d] = f2bf(acc[m][n][r]);
      }
}

// ---------------- K5: rv4 — rv einsum via global_load_lds DMA ----------------
// wave w stages rows {c*16 + w*4 .. +3} (1KB/wave call, wave-private dbuf);
// thread (jsub=lane>>4, d4=(lane&15)*4) consumes row w*4+jsub each chunk.
// Probs held bf16 in LDS [j*12+h]; partials overlay the stage area at the end.
__global__ __launch_bounds__(256) void k_rv4(const float* __restrict__ relation_v,
                                             const uint16_t* __restrict__ wprob,
                                             uint16_t* __restrict__ rv_bf) {
  __shared__ uint16_t wTb[6144];  // [j*12+h] bf16, 12 KB
  __shared__ float vstage[2048];  // stage[2][4][256] 8 KB; later partials [4][8][64]
  const int b = blockIdx.x >> 9, i = blockIdx.x & 511;
  const int t = threadIdx.x;
  const int wave = t >> 6, lane = t & 63;
  // P0: probs (bf16, raw) -> wTb
  for (int jj = t; jj < 512; jj += 256) {
#pragma unroll
    for (int h = 0; h < 8; ++h)
      wTb[jj * 12 + h] = wprob[(((size_t)b * 8 + h) * 512 + i) * 512 + jj];
  }
  __syncthreads();
  const int jsub = lane >> 4, d4 = (lane & 15) * 4;
  const float* rvb = relation_v + ((size_t)b * 512 + i) * 32768;
  f32x4 racc[8];
#pragma unroll
  for (int h = 0; h < 8; ++h) racc[h] = f32x4{0.f, 0.f, 0.f, 0.f};
  {
    auto STAGE = [&](int c, int buf) {
      const float* g = rvb + (size_t)(c * 16 + wave * 4 + jsub) * 64 + d4;
      gload_lds16(g, &vstage[buf * 1024 + wave * 256]);
    };
    STAGE(0, 0);
    int buf = 0;
#pragma unroll 4
    for (int c = 0; c < 32; ++c) {
      if (c < 31) {
        STAGE(c + 1, buf ^ 1);
        asm volatile("s_waitcnt vmcnt(1)" ::: "memory");
      } else {
        asm volatile("s_waitcnt vmcnt(0)" ::: "memory");
      }
      __builtin_amdgcn_sched_barrier(0);
      int j = c * 16 + wave * 4 + jsub;
      f32x4 rv4 = *(const f32x4*)&vstage[buf * 1024 + wave * 256 + jsub * 64 + d4];
      uint2 wlo = *(const uint2*)&wTb[j * 12];
      uint2 whi = *(const uint2*)&wTb[j * 12 + 4];
      uint16_t tw[8];
      *(uint2*)tw = wlo;
      *(uint2*)(tw + 4) = whi;
#pragma unroll
      for (int h = 0; h < 4; ++h) {
        racc[h] += bf2f(tw[h]) * rv4;
        racc[4 + h] += bf2f(tw[4 + h]) * rv4;
      }
      buf ^= 1;
    }
  }
  // reduce over jsub groups (lanes l, l^16, l^32, l^48)
#pragma unroll
  for (int h = 0; h < 8; ++h)
#pragma unroll
    for (int c = 0; c < 4; ++c) {
      racc[h][c] += __shfl_xor(racc[h][c], 16);
      racc[h][c] += __shfl_xor(racc[h][c], 32);
    }
  __syncthreads();  // all stage reads done; vstage becomes partials [w][h][d]
  if (lane < 16) {
#pragma unroll
    for (int h = 0; h < 8; ++h)
      *(f32x4*)&vstage[(wave * 8 + h) * 64 + (lane & 15) * 4] = racc[h];
  }
  __syncthreads();
  for (int e = t; e < 512; e += 256) {
    int h = e >> 6, d = e & 63;
    float s = vstage[(0 * 8 + h) * 64 + d] + vstage[(1 * 8 + h) * 64 + d] +
              vstage[(2 * 8 + h) * 64 + d] + vstage[(3 * 8 + h) * 64 + d];
    rv_bf[((size_t)i * 4 + b) * 512 + h * 64 + d] = f2bf(s);
  }
}

// ---------------- K6: out_proj bf16 MFMA, dual-A (pv+rv) ----------------
__global__ __launch_bounds__(256) void k_outproj(const uint16_t* __restrict__ rv_a,
                                                 const uint16_t* __restrict__ pv_a,
                                                 const uint16_t* __restrict__ wo_bf,
                                                 const float* __restrict__ bias,
                                                 float* __restrict__ out) {
  const int wave = threadIdx.x >> 6, lane = threadIdx.x & 63;
  const int wr = wave >> 1, wc = wave & 1;
  const int rif = lane & 15, kg = lane >> 4;
  const int rbase = blockIdx.x * 64 + wr * 32;
  const int cbase = blockIdx.y * 64 + wc * 32;
  f32x4 acc[2][2] = {};
  for (int ks = 0; ks < 512; ks += 32) {
    int kofs = ks + kg * 8;
    short8 A[2], Bb[2];
#pragma unroll
    for (int m = 0; m < 2; ++m) {
      size_t idx = (size_t)(rbase + m * 16 + rif) * 512 + kofs;
      short8 p = ld8(pv_a + idx);
      short8 rr = ld8(rv_a + idx);
      uint16_t tb[8];
#pragma unroll
      for (int e = 0; e < 8; ++e)
        tb[e] = f2bf(bf2f((uint16_t)p[e]) + bf2f((uint16_t)rr[e]));
      A[m] = *(const short8*)tb;
    }
#pragma unroll
    for (int n = 0; n < 2; ++n) Bb[n] = ld8(wo_bf + (size_t)(cbase + n * 16 + rif) * 512 + kofs);
#pragma unroll
    for (int m = 0; m < 2; ++m)
#pragma unroll
      for (int n = 0; n < 2; ++n) acc[m][n] = MFMA(A[m], Bb[n], acc[m][n]);
  }
#pragma unroll
  for (int m = 0; m < 2; ++m)
#pragma unroll
    for (int n = 0; n < 2; ++n)
#pragma unroll
      for (int r = 0; r < 4; ++r) {
        int row = rbase + m * 16 + kg * 4 + r;
        int col = cbase + n * 16 + rif;
        out[(size_t)row * 512 + col] = acc[m][n][r] + bias[col];
      }
}

extern "C" void kernel_launch(void* const* d_in, const int* in_sizes, int n_in,
                              void* d_out, int out_size, void* d_ws, size_t ws_size,
                              hipStream_t stream) {
  const float* query = (const float*)d_in[0];
  const float* relation_k = (const float*)d_in[1];
  const float* relation_v = (const float*)d_in[2];
  const float* in_w = (const float*)d_in[3];
  const float* in_b = (const float*)d_in[4];
  const float* out_w = (const float*)d_in[5];
  const float* out_b = (const float*)d_in[6];
  float* out = (float*)d_out;
  char* ws = (char*)d_ws;

  uint16_t* a_hi  = (uint16_t*)(ws + 0);          // 2 MB
  uint16_t* a_lo  = (uint16_t*)(ws + 2097152);    // 2 MB
  uint16_t* w_hi  = (uint16_t*)(ws + 4194304);    // 1.5 MB
  uint16_t* w_lo  = (uint16_t*)(ws + 5767168);    // 1.5 MB
  uint16_t* wo_bf = (uint16_t*)(ws + 7340032);    // 0.5 MB
  float*    q_s   = (float*)   (ws + 7864320);    // 4 MB  (B,H,L,D) f32 scaled
  uint16_t* q_bf  = (uint16_t*)(ws + 12058624);   // 2 MB
  uint16_t* k_bf  = (uint16_t*)(ws + 14155776);   // 2 MB
  uint16_t* v_bf  = (uint16_t*)(ws + 16252928);   // 2 MB
  uint16_t* rv_bf = (uint16_t*)(ws + 18350080);   // 2 MB  (L,B,E)
  uint16_t* pv_bf = (uint16_t*)(ws + 20447232);   // 2 MB  (L,B,E)
  uint16_t* wprob = (uint16_t*)(ws + 22544384);   // 16 MB (B,H,L,L) bf16
  __half*   sc_h  = (__half*)  (ws + 39321600);   // 8 MB  (B,H,L,L) fp16

  k_conv_all<<<dim3(2048), 256, 0, stream>>>(in_w, query, out_w, w_hi, w_lo, a_hi, a_lo, wo_bf);
  k_inproj<<<dim3(32, 24), 256, 0, stream>>>(a_hi, a_lo, w_hi, w_lo, in_b, q_s, q_bf, k_bf, v_bf);
  k_scores<<<dim3(32, 8, 8), 256, 0, stream>>>(q_bf, k_bf, sc_h);
  k_rksm5<<<dim3(2048), 256, 0, stream>>>(relation_k, q_s, sc_h, wprob);
  k_pv<<<dim3(32, 8), 256, 0, stream>>>(wprob, v_bf, pv_bf);
  k_rv4<<<dim3(2048), 256, 0, stream>>>(relation_v, wprob, rv_bf);
  k_outproj<<<dim3(32, 8), 256, 0, stream>>>(rv_bf, pv_bf, wo_bf, out_b, out);
}

// Round 12
// 193.108 us; speedup vs baseline: 1.1134x; 1.1134x over previous
//
#include <hip/hip_runtime.h>
#include <hip/hip_fp16.h>
#include <stdint.h>

// L=512, B=4, E=512, H=8, D=64
// Pipeline (7 launches) — best configuration (R9, 193.7us):
//  K0 conv_all : fp32 -> bf16 (hi/lo split) for in_w, query; hi for out_w
//  K1 inproj   : qkv = query @ W^T + b (split-bf16 MFMA) -> q_s f32, q/k/v bf16 (B,H,L,D)
//  K2 scores   : content scores = q.k^T per (b,h) (bf16 MFMA) -> scores fp16
//  K3 rksm3    : per (b,i): rk-einsum (NT f32x4, 8-deep, shfl d-reduce) + softmax -> wprob
//  K4 pv       : attn_pv = w @ v per (b,h) (bf16 MFMA) -> pv_bf (L,B,E)
//  K5 rv2      : per (b,i): rv-einsum (8-deep normal f32x4 loads) -> rv_bf (L,B,E)
//  K6 outproj  : out = (rv_bf+pv_bf) @ Wo^T + b (bf16 MFMA) -> d_out fp32
//
// Roofline note: streams k_rksm3 + k_rv2 must read 512 MB (relation_k +
// relation_v) from HBM; sustained read rate ~3.3 TB/s (== read component of
// the m13 copy ubench) -> ~155us floor; + ~40us GEMM chain & launches = ~195us.

typedef short short8 __attribute__((ext_vector_type(8)));
typedef float f32x4 __attribute__((ext_vector_type(4)));
typedef unsigned short u16x4 __attribute__((ext_vector_type(4)));

static __device__ __forceinline__ uint16_t f2bf(float f) {
  uint32_t u = __float_as_uint(f);
  uint32_t r = (u + 0x7FFFu + ((u >> 16) & 1u)) >> 16;
  return (uint16_t)r;
}
static __device__ __forceinline__ float bf2f(uint16_t h) {
  return __uint_as_float(((uint32_t)h) << 16);
}
static __device__ __forceinline__ short8 ld8(const uint16_t* p) {
  return *(const short8*)p;
}
#define MFMA(a, b, c) __builtin_amdgcn_mfma_f32_16x16x32_bf16((a), (b), (c), 0, 0, 0)

// ---------------- K0: merged fp32 -> bf16 conversions ----------------
__global__ __launch_bounds__(256) void k_conv_all(
    const float* __restrict__ in_w, const float* __restrict__ query,
    const float* __restrict__ out_w, uint16_t* __restrict__ w_hi,
    uint16_t* __restrict__ w_lo, uint16_t* __restrict__ a_hi,
    uint16_t* __restrict__ a_lo, uint16_t* __restrict__ wo_bf) {
  int e = (blockIdx.x * 256 + threadIdx.x) * 4;
  if (e < 786432) {
    f32x4 v = *(const f32x4*)(in_w + e);
    u16x4 hi, lo;
#pragma unroll
    for (int k = 0; k < 4; ++k) {
      hi[k] = f2bf(v[k]);
      lo[k] = f2bf(v[k] - bf2f(hi[k]));
    }
    *(u16x4*)(w_hi + e) = hi;
    *(u16x4*)(w_lo + e) = lo;
  } else if (e < 786432 + 1048576) {
    int o = e - 786432;
    f32x4 v = *(const f32x4*)(query + o);
    u16x4 hi, lo;
#pragma unroll
    for (int k = 0; k < 4; ++k) {
      hi[k] = f2bf(v[k]);
      lo[k] = f2bf(v[k] - bf2f(hi[k]));
    }
    *(u16x4*)(a_hi + o) = hi;
    *(u16x4*)(a_lo + o) = lo;
  } else {
    int o = e - 1835008;
    f32x4 v = *(const f32x4*)(out_w + o);
    u16x4 hi;
#pragma unroll
    for (int k = 0; k < 4; ++k) hi[k] = f2bf(v[k]);
    *(u16x4*)(wo_bf + o) = hi;
  }
}

// ---------------- K1: in_proj split-bf16 MFMA GEMM ----------------
__global__ __launch_bounds__(256) void k_inproj(
    const uint16_t* __restrict__ a_hi, const uint16_t* __restrict__ a_lo,
    const uint16_t* __restrict__ w_hi, const uint16_t* __restrict__ w_lo,
    const float* __restrict__ bias, float* __restrict__ q_s,
    uint16_t* __restrict__ q_bf, uint16_t* __restrict__ k_bf,
    uint16_t* __restrict__ v_bf) {
  const int wave = threadIdx.x >> 6, lane = threadIdx.x & 63;
  const int wr = wave >> 1, wc = wave & 1;
  const int rif = lane & 15, kg = lane >> 4;
  const int rbase = blockIdx.x * 64 + wr * 32;
  const int cbase = blockIdx.y * 64 + wc * 32;
  f32x4 acc[2][2] = {};
  for (int ks = 0; ks < 512; ks += 32) {
    int kofs = ks + kg * 8;
    short8 aH[2], aL[2], bH[2], bL[2];
#pragma unroll
    for (int m = 0; m < 2; ++m) {
      size_t idx = (size_t)(rbase + m * 16 + rif) * 512 + kofs;
      aH[m] = ld8(a_hi + idx);
      aL[m] = ld8(a_lo + idx);
    }
#pragma unroll
    for (int n = 0; n < 2; ++n) {
      size_t idx = (size_t)(cbase + n * 16 + rif) * 512 + kofs;
      bH[n] = ld8(w_hi + idx);
      bL[n] = ld8(w_lo + idx);
    }
#pragma unroll
    for (int m = 0; m < 2; ++m)
#pragma unroll
      for (int n = 0; n < 2; ++n) {
        acc[m][n] = MFMA(aH[m], bH[n], acc[m][n]);
        acc[m][n] = MFMA(aH[m], bL[n], acc[m][n]);
        acc[m][n] = MFMA(aL[m], bH[n], acc[m][n]);
      }
  }
#pragma unroll
  for (int m = 0; m < 2; ++m)
#pragma unroll
    for (int n = 0; n < 2; ++n)
#pragma unroll
      for (int r = 0; r < 4; ++r) {
        int row = rbase + m * 16 + kg * 4 + r;
        int col = cbase + n * 16 + rif;
        float val = acc[m][n][r] + bias[col];
        int l = row >> 2, b = row & 3;
        int sel = col >> 9, h = (col >> 6) & 7, d = col & 63;
        size_t oidx = ((size_t)(b * 8 + h) * 512 + l) * 64 + d;
        if (sel == 0) {
          val *= 0.125f;  // 1/sqrt(64)
          q_s[oidx] = val;
          q_bf[oidx] = f2bf(val);
        } else if (sel == 1) {
          k_bf[oidx] = f2bf(val);
        } else {
          v_bf[oidx] = f2bf(val);
        }
      }
}

// ---------------- K2: content scores per (b,h), fp16 output ----------------
__global__ __launch_bounds__(256) void k_scores(const uint16_t* __restrict__ q_bf,
                                                const uint16_t* __restrict__ k_bf,
                                                __half* __restrict__ scores) {
  const int bh = blockIdx.x;
  const uint16_t* qb = q_bf + (size_t)bh * 512 * 64;
  const uint16_t* kb = k_bf + (size_t)bh * 512 * 64;
  const int wave = threadIdx.x >> 6, lane = threadIdx.x & 63;
  const int wr = wave >> 1, wc = wave & 1;
  const int rif = lane & 15, kg = lane >> 4;
  const int ibase = blockIdx.y * 64 + wr * 32;
  const int jbase = blockIdx.z * 64 + wc * 32;
  f32x4 acc[2][2] = {};
#pragma unroll
  for (int ks = 0; ks < 64; ks += 32) {
    int kofs = ks + kg * 8;
    short8 A[2], Bb[2];
#pragma unroll
    for (int m = 0; m < 2; ++m) A[m] = ld8(qb + (size_t)(ibase + m * 16 + rif) * 64 + kofs);
#pragma unroll
    for (int n = 0; n < 2; ++n) Bb[n] = ld8(kb + (size_t)(jbase + n * 16 + rif) * 64 + kofs);
#pragma unroll
    for (int m = 0; m < 2; ++m)
#pragma unroll
      for (int n = 0; n < 2; ++n) acc[m][n] = MFMA(A[m], Bb[n], acc[m][n]);
  }
  __half* sc = scores + (size_t)bh * 512 * 512;
#pragma unroll
  for (int m = 0; m < 2; ++m)
#pragma unroll
    for (int n = 0; n < 2; ++n)
#pragma unroll
      for (int r = 0; r < 4; ++r)
        sc[(size_t)(ibase + m * 16 + kg * 4 + r) * 512 + (jbase + n * 16 + rif)] =
            __float2half(acc[m][n][r]);
}

// ---------------- K3: rksm3 — rk einsum (NT, 8-deep, shfl d-reduce) + softmax ----------------
// wave w owns j in [w*128, w*128+128); lane&31 = j-quad, lane>>5 = d-half.
// d-halves combined via shfl_xor(32) — no LDS round-trip, no extra syncs.
__global__ __launch_bounds__(256) void k_rksm3(
    const float* __restrict__ relation_k, const float* __restrict__ q_s,
    const __half* __restrict__ scores, uint16_t* __restrict__ wprob) {
  __shared__ float qh[512];   // [d][h] 2 KB
  __shared__ float sx[4096];  // [h][j] 16 KB
  const int b = blockIdx.x >> 9, i = blockIdx.x & 511;
  const int t = threadIdx.x;
  const int wave = t >> 6, lane = t & 63;
  // P1: q into LDS [d][h]
  for (int e = t; e < 512; e += 256) {
    int h = e >> 6, d = e & 63;
    qh[d * 8 + h] = q_s[(((size_t)b * 8 + h) * 512 + i) * 64 + d];
  }
  __syncthreads();
  // P2: rk einsum, 8-deep NT batches; dh = lane>>5 covers d in [dh*32, dh*32+32)
  const int jq = lane & 31, dh = lane >> 5;
  const int j0 = wave * 128 + jq * 4;
  f32x4 acc[8];
#pragma unroll
  for (int h = 0; h < 8; ++h) acc[h] = f32x4{0.f, 0.f, 0.f, 0.f};
  {
    const float* rkp =
        relation_k + ((size_t)b * 512 + i) * 32768 + (size_t)dh * 32 * 512 + j0;
    const float* qp = qh + dh * 32 * 8;
    for (int dd0 = 0; dd0 < 32; dd0 += 8) {
      f32x4 kv[8];
#pragma unroll
      for (int u = 0; u < 8; ++u)
        kv[u] = __builtin_nontemporal_load((const f32x4*)(rkp + (size_t)(dd0 + u) * 512));
#pragma unroll
      for (int u = 0; u < 8; ++u) {
        f32x4 qA = *(const f32x4*)(qp + (dd0 + u) * 8);
        f32x4 qB = *(const f32x4*)(qp + (dd0 + u) * 8 + 4);
#pragma unroll
        for (int h = 0; h < 4; ++h) {
          acc[h] += qA[h] * kv[u];
          acc[4 + h] += qB[h] * kv[u];
        }
      }
    }
  }
  // combine d-halves in-register (lane l <-> l^32)
#pragma unroll
  for (int h = 0; h < 8; ++h)
#pragma unroll
    for (int c = 0; c < 4; ++c) acc[h][c] += __shfl_xor(acc[h][c], 32);
  if (dh == 0) {
#pragma unroll
    for (int h = 0; h < 8; ++h) *(f32x4*)&sx[h * 512 + j0] = acc[h];
  }
  __syncthreads();
  // P3: softmax (wave -> heads 2w, 2w+1); write wprob bf16
#pragma unroll
  for (int hh = 0; hh < 2; ++hh) {
    int h = wave * 2 + hh;
    const __half* srow = scores + (((size_t)b * 8 + h) * 512 + i) * 512;
    float s[8], m = -1e30f;
#pragma unroll
    for (int jj = 0; jj < 8; ++jj) {
      int j = jj * 64 + lane;
      s[jj] = __half2float(srow[j]) + sx[h * 512 + j];
      m = fmaxf(m, s[jj]);
    }
    for (int o = 32; o > 0; o >>= 1) m = fmaxf(m, __shfl_xor(m, o));
    float ex[8], sum = 0.f;
#pragma unroll
    for (int jj = 0; jj < 8; ++jj) {
      ex[jj] = __expf(s[jj] - m);
      sum += ex[jj];
    }
    for (int o = 32; o > 0; o >>= 1) sum += __shfl_xor(sum, o);
    float r = 1.f / sum;
    uint16_t* wrow = wprob + (((size_t)b * 8 + h) * 512 + i) * 512;
#pragma unroll
    for (int jj = 0; jj < 8; ++jj) wrow[jj * 64 + lane] = f2bf(ex[jj] * r);
  }
}

// ---------------- K4: PV MFMA per (b,h), strided v loads ----------------
__global__ __launch_bounds__(256) void k_pv(const uint16_t* __restrict__ w_bf,
                                            const uint16_t* __restrict__ v_bf,
                                            uint16_t* __restrict__ pv_bf) {
  const int bh = blockIdx.x;
  const int b = bh >> 3, h = bh & 7;
  const uint16_t* wb = w_bf + (size_t)bh * 512 * 512;
  const uint16_t* vb = v_bf + (size_t)bh * 512 * 64;  // [j][d]
  const int wave = threadIdx.x >> 6, lane = threadIdx.x & 63;
  const int wr = wave >> 1, wc = wave & 1;
  const int rif = lane & 15, kg = lane >> 4;
  const int ibase = blockIdx.y * 64 + wr * 32;
  const int dbase = wc * 32;
  f32x4 acc[2][2] = {};
  for (int ks = 0; ks < 512; ks += 32) {
    int kofs = ks + kg * 8;
    short8 A[2], Bb[2];
#pragma unroll
    for (int m = 0; m < 2; ++m) A[m] = ld8(wb + (size_t)(ibase + m * 16 + rif) * 512 + kofs);
#pragma unroll
    for (int n = 0; n < 2; ++n) {
      uint16_t tb[8];
#pragma unroll
      for (int e = 0; e < 8; ++e) tb[e] = vb[(size_t)(kofs + e) * 64 + dbase + n * 16 + rif];
      Bb[n] = *(const short8*)tb;
    }
#pragma unroll
    for (int m = 0; m < 2; ++m)
#pragma unroll
      for (int n = 0; n < 2; ++n) acc[m][n] = MFMA(A[m], Bb[n], acc[m][n]);
  }
#pragma unroll
  for (int m = 0; m < 2; ++m)
#pragma unroll
    for (int n = 0; n < 2; ++n)
#pragma unroll
      for (int r = 0; r < 4; ++r) {
        int i = ibase + m * 16 + kg * 4 + r;
        int d = dbase + n * 16 + rif;
        pv_bf[((size_t)i * 4 + b) * 512 + h * 64 + d] = f2bf(acc[m][n][r]);
      }
}

// ---------------- K5: rv2 — rv einsum (8-deep normal loads) ----------------
__global__ __launch_bounds__(256) void k_rv2(const float* __restrict__ relation_v,
                                             const uint16_t* __restrict__ wprob,
                                             uint16_t* __restrict__ rv_bf) {
  __shared__ float wT[4608];  // 18 KB: probs padded [j*9+h]; then partials [w][h][d]
  const int b = blockIdx.x >> 9, i = blockIdx.x & 511;
  const int t = threadIdx.x;
  const int wave = t >> 6, lane = t & 63;
  // P0: wprob (bf16) -> wT [j*9+h] f32
  for (int jj = t; jj < 512; jj += 256) {
    uint16_t tmp[8];
#pragma unroll
    for (int h = 0; h < 8; ++h)
      tmp[h] = wprob[(((size_t)b * 8 + h) * 512 + i) * 512 + jj];
#pragma unroll
    for (int h = 0; h < 8; ++h) wT[jj * 9 + h] = bf2f(tmp[h]);
  }
  __syncthreads();
  // P1: main stream, 8-deep load batches
  f32x4 racc[8];
#pragma unroll
  for (int h = 0; h < 8; ++h) racc[h] = f32x4{0.f, 0.f, 0.f, 0.f};
  {
    const int jsub = lane >> 4, d4 = (lane & 15) * 4;
    const float* rvb = relation_v + ((size_t)b * 512 + i) * 32768;
    for (int s8 = 0; s8 < 32; s8 += 8) {
      f32x4 rvv[8];
      int js[8];
#pragma unroll
      for (int u = 0; u < 8; ++u) {
        js[u] = (s8 + u) * 16 + wave * 4 + jsub;
        rvv[u] = *(const f32x4*)(rvb + (size_t)js[u] * 64 + d4);
      }
#pragma unroll
      for (int u = 0; u < 8; ++u) {
        f32x4 w0 = *(const f32x4*)&wT[js[u] * 9];
        f32x4 w1 = *(const f32x4*)&wT[js[u] * 9 + 4];
#pragma unroll
        for (int h = 0; h < 4; ++h) {
          racc[h] += w0[h] * rvv[u];
          racc[4 + h] += w1[h] * rvv[u];
        }
      }
    }
  }
  // reduce over jsub groups (lanes l, l^16, l^32, l^48)
#pragma unroll
  for (int h = 0; h < 8; ++h)
#pragma unroll
    for (int c = 0; c < 4; ++c) {
      racc[h][c] += __shfl_xor(racc[h][c], 16);
      racc[h][c] += __shfl_xor(racc[h][c], 32);
    }
  __syncthreads();  // wT reads done; reuse as partials [w][h][d]
  if (lane < 16) {
#pragma unroll
    for (int h = 0; h < 8; ++h)
      *(f32x4*)&wT[(wave * 8 + h) * 64 + (lane & 15) * 4] = racc[h];
  }
  __syncthreads();
  // P2: reduce 4 waves, write rv_bf (L,B,E)
  for (int e = t; e < 512; e += 256) {
    int h = e >> 6, d = e & 63;
    float s = wT[(0 * 8 + h) * 64 + d] + wT[(1 * 8 + h) * 64 + d] +
              wT[(2 * 8 + h) * 64 + d] + wT[(3 * 8 + h) * 64 + d];
    rv_bf[((size_t)i * 4 + b) * 512 + h * 64 + d] = f2bf(s);
  }
}

// ---------------- K6: out_proj bf16 MFMA, dual-A (pv+rv) ----------------
__global__ __launch_bounds__(256) void k_outproj(const uint16_t* __restrict__ rv_a,
                                                 const uint16_t* __restrict__ pv_a,
                                                 const uint16_t* __restrict__ wo_bf,
                                                 const float* __restrict__ bias,
                                                 float* __restrict__ out) {
  const int wave = threadIdx.x >> 6, lane = threadIdx.x & 63;
  const int wr = wave >> 1, wc = wave & 1;
  const int rif = lane & 15, kg = lane >> 4;
  const int rbase = blockIdx.x * 64 + wr * 32;
  const int cbase = blockIdx.y * 64 + wc * 32;
  f32x4 acc[2][2] = {};
  for (int ks = 0; ks < 512; ks += 32) {
    int kofs = ks + kg * 8;
    short8 A[2], Bb[2];
#pragma unroll
    for (int m = 0; m < 2; ++m) {
      size_t idx = (size_t)(rbase + m * 16 + rif) * 512 + kofs;
      short8 p = ld8(pv_a + idx);
      short8 rr = ld8(rv_a + idx);
      uint16_t tb[8];
#pragma unroll
      for (int e = 0; e < 8; ++e)
        tb[e] = f2bf(bf2f((uint16_t)p[e]) + bf2f((uint16_t)rr[e]));
      A[m] = *(const short8*)tb;
    }
#pragma unroll
    for (int n = 0; n < 2; ++n) Bb[n] = ld8(wo_bf + (size_t)(cbase + n * 16 + rif) * 512 + kofs);
#pragma unroll
    for (int m = 0; m < 2; ++m)
#pragma unroll
      for (int n = 0; n < 2; ++n) acc[m][n] = MFMA(A[m], Bb[n], acc[m][n]);
  }
#pragma unroll
  for (int m = 0; m < 2; ++m)
#pragma unroll
    for (int n = 0; n < 2; ++n)
#pragma unroll
      for (int r = 0; r < 4; ++r) {
        int row = rbase + m * 16 + kg * 4 + r;
        int col = cbase + n * 16 + rif;
        out[(size_t)row * 512 + col] = acc[m][n][r] + bias[col];
      }
}

extern "C" void kernel_launch(void* const* d_in, const int* in_sizes, int n_in,
                              void* d_out, int out_size, void* d_ws, size_t ws_size,
                              hipStream_t stream) {
  const float* query = (const float*)d_in[0];
  const float* relation_k = (const float*)d_in[1];
  const float* relation_v = (const float*)d_in[2];
  const float* in_w = (const float*)d_in[3];
  const float* in_b = (const float*)d_in[4];
  const float* out_w = (const float*)d_in[5];
  const float* out_b = (const float*)d_in[6];
  float* out = (float*)d_out;
  char* ws = (char*)d_ws;

  uint16_t* a_hi  = (uint16_t*)(ws + 0);          // 2 MB
  uint16_t* a_lo  = (uint16_t*)(ws + 2097152);    // 2 MB
  uint16_t* w_hi  = (uint16_t*)(ws + 4194304);    // 1.5 MB
  uint16_t* w_lo  = (uint16_t*)(ws + 5767168);    // 1.5 MB
  uint16_t* wo_bf = (uint16_t*)(ws + 7340032);    // 0.5 MB
  float*    q_s   = (float*)   (ws + 7864320);    // 4 MB  (B,H,L,D) f32 scaled
  uint16_t* q_bf  = (uint16_t*)(ws + 12058624);   // 2 MB
  uint16_t* k_bf  = (uint16_t*)(ws + 14155776);   // 2 MB
  uint16_t* v_bf  = (uint16_t*)(ws + 16252928);   // 2 MB
  uint16_t* rv_bf = (uint16_t*)(ws + 18350080);   // 2 MB  (L,B,E)
  uint16_t* pv_bf = (uint16_t*)(ws + 20447232);   // 2 MB  (L,B,E)
  uint16_t* wprob = (uint16_t*)(ws + 22544384);   // 16 MB (B,H,L,L) bf16
  __half*   sc_h  = (__half*)  (ws + 39321600);   // 8 MB  (B,H,L,L) fp16

  k_conv_all<<<dim3(2048), 256, 0, stream>>>(in_w, query, out_w, w_hi, w_lo, a_hi, a_lo, wo_bf);
  k_inproj<<<dim3(32, 24), 256, 0, stream>>>(a_hi, a_lo, w_hi, w_lo, in_b, q_s, q_bf, k_bf, v_bf);
  k_scores<<<dim3(32, 8, 8), 256, 0, stream>>>(q_bf, k_bf, sc_h);
  k_rksm3<<<dim3(2048), 256, 0, stream>>>(relation_k, q_s, sc_h, wprob);
  k_pv<<<dim3(32, 8), 256, 0, stream>>>(wprob, v_bf, pv_bf);
  k_rv2<<<dim3(2048), 256, 0, stream>>>(relation_v, wprob, rv_bf);
  k_outproj<<<dim3(32, 8), 256, 0, stream>>>(rv_bf, pv_bf, wo_bf, out_b, out);
}